// Round 1
// baseline (1277.757 us; speedup 1.0000x reference)
//
#include <hip/hip_runtime.h>

#define AS1 __attribute__((address_space(1)))
#define AS3 __attribute__((address_space(3)))

typedef __attribute__((ext_vector_type(8))) __bf16 bf16x8;
typedef __attribute__((ext_vector_type(4))) float f32x4;

__device__ __forceinline__ float bf2f(unsigned short u) {
    unsigned v = ((unsigned)u) << 16;
    float f;
    __builtin_memcpy(&f, &v, 4);
    return f;
}
__device__ __forceinline__ unsigned short f2bf(float f) {
    unsigned v;
    __builtin_memcpy(&v, &f, 4);
    unsigned r = (v + 0x7FFFu + ((v >> 16) & 1u)) >> 16;
    return (unsigned short)r;
}

// ---------------------------------------------------------------------------
// Kernel 1: LayerNorm of x / y / inial_y2x / inial_x2y -> bf16 [65536][768]
// rows [0,16384)=x, [16384,32768)=y, [32768,49152)=y2x, [49152,65536)=x2y
// ---------------------------------------------------------------------------
__global__ __launch_bounds__(192) void ln4_kernel(
    const float* __restrict__ x, const float* __restrict__ y,
    const float* __restrict__ y2x, const float* __restrict__ x2y,
    const float* __restrict__ g, const float* __restrict__ bb,
    unsigned short* __restrict__ out)
{
    __shared__ float red[2][3];
    int row = blockIdx.x;
    int c = row >> 14, rb = row & 16383;
    const float* src = (c == 0 ? x : c == 1 ? y : c == 2 ? y2x : x2y) + (size_t)rb * 768;
    int t = threadIdx.x;
    float4 v = ((const float4*)src)[t];
    float s = v.x + v.y + v.z + v.w;
    float sq = v.x * v.x + v.y * v.y + v.z * v.z + v.w * v.w;
#pragma unroll
    for (int o = 32; o >= 1; o >>= 1) { s += __shfl_xor(s, o); sq += __shfl_xor(sq, o); }
    int wid = t >> 6, lane = t & 63;
    if (lane == 0) { red[0][wid] = s; red[1][wid] = sq; }
    __syncthreads();
    float S = red[0][0] + red[0][1] + red[0][2];
    float SQ = red[1][0] + red[1][1] + red[1][2];
    float mu = S * (1.0f / 768.0f);
    float var = SQ * (1.0f / 768.0f) - mu * mu;
    float rs = rsqrtf(var + 1e-6f);
    float4 gv = ((const float4*)g)[t];
    float4 bv = ((const float4*)bb)[t];
    ushort4 o4;
    o4.x = f2bf((v.x - mu) * rs * gv.x + bv.x);
    o4.y = f2bf((v.y - mu) * rs * gv.y + bv.y);
    o4.z = f2bf((v.z - mu) * rs * gv.z + bv.z);
    o4.w = f2bf((v.w - mu) * rs * gv.w + bv.w);
    ((ushort4*)(out + (size_t)row * 768))[t] = o4;
}

// ---------------------------------------------------------------------------
// Kernel 2: transpose f32 [R][C] -> bf16 [C][R]
// ---------------------------------------------------------------------------
__global__ __launch_bounds__(256) void transpose_f32_to_bf16(
    const float* __restrict__ in, unsigned short* __restrict__ out, int R, int C)
{
    __shared__ float tile[32][33];
    int tilesC = C >> 5;
    int r0 = (blockIdx.x / tilesC) << 5;
    int c0 = (blockIdx.x % tilesC) << 5;
    int tx = threadIdx.x & 31, ty = threadIdx.x >> 5;
#pragma unroll
    for (int i = ty; i < 32; i += 8)
        tile[i][tx] = in[(size_t)(r0 + i) * C + c0 + tx];
    __syncthreads();
#pragma unroll
    for (int i = ty; i < 32; i += 8)
        out[(size_t)(c0 + i) * R + r0 + tx] = f2bf(tile[tx][i]);
}

// ---------------------------------------------------------------------------
// Kernel 3: bf16 MFMA GEMM, C = A[MxK] * B (B given as BT [N][K], row-major K)
// 128x128 tile, BK=64, 256 threads (4 waves, 2x2), 16x16x32 MFMA.
// EPI=false: out bf16.  EPI=true: out f32 = acc + bias[col] + resid[row][col].
// M%128==0, N%128==0, K%64==0 (holds for all our shapes).
// ---------------------------------------------------------------------------
template <bool EPI>
__global__ __launch_bounds__(256, 3) void gemm_bt(
    const unsigned short* __restrict__ A, const unsigned short* __restrict__ BT,
    void* __restrict__ outp, const float* __restrict__ bias,
    const unsigned short* __restrict__ resid, int M, int N, int K)
{
    __shared__ unsigned short sA[128 * 64];
    __shared__ unsigned short sB[128 * 64];
    const int tid = threadIdx.x;
    const int lane = tid & 63;
    const int wid = tid >> 6;
    const int wm = wid >> 1, wn = wid & 1;
    const int ntn = N >> 7;
    const int tm = blockIdx.x / ntn, tn = blockIdx.x % ntn;
    const int rowA0 = tm << 7, rowB0 = tn << 7;

    f32x4 acc[4][4];
    const f32x4 zero = {0.f, 0.f, 0.f, 0.f};
#pragma unroll
    for (int i = 0; i < 4; ++i)
#pragma unroll
        for (int j = 0; j < 4; ++j) acc[i][j] = zero;

    for (int k0 = 0; k0 < K; k0 += 64) {
        // stage A and B tiles: 16 KiB each, 4 rounds x 256 threads x 16B
#pragma unroll
        for (int r = 0; r < 4; ++r) {
            int idx = (r << 8) + tid;            // 0..1023 chunk of 16B
            int arow = idx >> 3;                 // 0..127
            int ce = (idx & 7) << 3;             // element offset in row (0..56)
            const unsigned short* gpA = A + (size_t)(rowA0 + arow) * K + k0 + ce;
            const unsigned short* gpB = BT + (size_t)(rowB0 + arow) * K + k0 + ce;
            __builtin_amdgcn_global_load_lds((const AS1 void*)gpA,
                                             (AS3 void*)((char*)sA + ((size_t)idx << 4)), 16, 0, 0);
            __builtin_amdgcn_global_load_lds((const AS1 void*)gpB,
                                             (AS3 void*)((char*)sB + ((size_t)idx << 4)), 16, 0, 0);
        }
        __syncthreads();
#pragma unroll
        for (int kk = 0; kk < 2; ++kk) {
            bf16x8 af[4], bfr[4];
            int kb = (kk << 6) + ((lane >> 4) << 4);  // byte offset within 128B row
#pragma unroll
            for (int i = 0; i < 4; ++i) {
                af[i]  = *(const bf16x8*)((const char*)sA + ((wm << 6) + (i << 4) + (lane & 15)) * 128 + kb);
                bfr[i] = *(const bf16x8*)((const char*)sB + ((wn << 6) + (i << 4) + (lane & 15)) * 128 + kb);
            }
#pragma unroll
            for (int i = 0; i < 4; ++i)
#pragma unroll
                for (int j = 0; j < 4; ++j)
                    acc[i][j] = __builtin_amdgcn_mfma_f32_16x16x32_bf16(af[i], bfr[j], acc[i][j], 0, 0, 0);
        }
        __syncthreads();
    }

    const int r4 = (lane >> 4) << 2;
    const int cc = lane & 15;
    if (EPI) {
        float* o = (float*)outp;
#pragma unroll
        for (int i = 0; i < 4; ++i)
#pragma unroll
            for (int j = 0; j < 4; ++j) {
                int col = rowB0 + (wn << 6) + (j << 4) + cc;
                float bcol = bias[col];
#pragma unroll
                for (int r = 0; r < 4; ++r) {
                    int row = rowA0 + (wm << 6) + (i << 4) + r4 + r;
                    size_t off = (size_t)row * N + col;
                    o[off] = acc[i][j][r] + bcol + bf2f(resid[off]);
                }
            }
    } else {
        unsigned short* o = (unsigned short*)outp;
#pragma unroll
        for (int i = 0; i < 4; ++i)
#pragma unroll
            for (int j = 0; j < 4; ++j) {
                int col = rowB0 + (wn << 6) + (j << 4) + cc;
#pragma unroll
                for (int r = 0; r < 4; ++r) {
                    int row = rowA0 + (wm << 6) + (i << 4) + r4 + r;
                    o[(size_t)row * N + col] = f2bf(acc[i][j][r]);
                }
            }
    }
}

// ---------------------------------------------------------------------------
// Kernel 4: per-row middle block for all 4 combos.
// qkv: [32768][2304] bf16 (rows 0..16383 = x, 16384..32767 = y; q|k|v each 768)
// lnres: [65536][768] bf16 LN'd residuals; fln out: [65536][768] bf16
// ---------------------------------------------------------------------------
__global__ __launch_bounds__(256) void block_middle(
    const unsigned short* __restrict__ qkv,
    const unsigned short* __restrict__ lnres,
    const float* __restrict__ Wpb, const float* __restrict__ bpb,
    const float* __restrict__ ln_g, const float* __restrict__ ln_b,
    unsigned short* __restrict__ fln)
{
    __shared__ float sW[96 * 96];
    __shared__ float sS[768];
    __shared__ float sG[768];
    __shared__ float red[2][4];
    const int tid = threadIdx.x;
    for (int i = tid; i < 96 * 96; i += 256) sW[i] = Wpb[i];
    const float scale = 0.1020620726159658f;  // 96^-0.5
    int row0 = blockIdx.x << 3;
    __syncthreads();
    for (int rr = 0; rr < 8; ++rr) {
        int grow = row0 + rr;
        int c = grow >> 14, b = grow & 16383;
        int qrow  = (c == 1 || c == 2) ? (16384 + b) : b;
        int kvrow = (c == 1 || c == 3) ? (16384 + b) : b;
        const unsigned short* qp = qkv + (size_t)qrow * 2304;
        const unsigned short* kp = qkv + (size_t)kvrow * 2304 + 768;
        const unsigned short* vp = qkv + (size_t)kvrow * 2304 + 1536;
        // phase 1: s = q*k*scale
#pragma unroll
        for (int s3 = 0; s3 < 3; ++s3) {
            int j = tid + (s3 << 8);
            sS[j] = bf2f(qp[j]) * bf2f(kp[j]) * scale;
        }
        __syncthreads();
        // phase 2: per-head softmax (8 heads x 96) and g = attn * v
        {
            int grp = tid >> 5, l = tid & 31;
            int base = grp * 96;
            float a = sS[base + l], d = sS[base + 32 + l], e = sS[base + 64 + l];
            float m = fmaxf(a, fmaxf(d, e));
#pragma unroll
            for (int o = 16; o >= 1; o >>= 1) m = fmaxf(m, __shfl_xor(m, o));
            float e0 = __expf(a - m), e1 = __expf(d - m), e2 = __expf(e - m);
            float ss = e0 + e1 + e2;
#pragma unroll
            for (int o = 16; o >= 1; o >>= 1) ss += __shfl_xor(ss, o);
            float inv = 1.0f / ss;
            const unsigned short* vph = vp + base;
            sG[base + l]      = e0 * inv * bf2f(vph[l]);
            sG[base + 32 + l] = e1 * inv * bf2f(vph[32 + l]);
            sG[base + 64 + l] = e2 * inv * bf2f(vph[64 + l]);
        }
        __syncthreads();
        // phase 3: f = g @ Wpb + bpb; t = f + res; LN(t) -> fln
        int j0 = tid, j1 = tid + 256, j2 = tid + 512;
        int h0 = j0 / 96, h1 = j1 / 96, h2 = j2 / 96;
        int o0 = j0 - h0 * 96, o1 = j1 - h1 * 96, o2 = j2 - h2 * 96;
        const float* g0 = sG + h0 * 96;
        const float* g1 = sG + h1 * 96;
        const float* g2 = sG + h2 * 96;
        float a0 = bpb[o0], a1 = bpb[o1], a2 = bpb[o2];
#pragma unroll 4
        for (int i = 0; i < 96; ++i) {
            a0 += g0[i] * sW[i * 96 + o0];
            a1 += g1[i] * sW[i * 96 + o1];
            a2 += g2[i] * sW[i * 96 + o2];
        }
        const unsigned short* rp = lnres + (size_t)grow * 768;
        float t0 = a0 + bf2f(rp[j0]);
        float t1 = a1 + bf2f(rp[j1]);
        float t2 = a2 + bf2f(rp[j2]);
        float s = t0 + t1 + t2, sq = t0 * t0 + t1 * t1 + t2 * t2;
#pragma unroll
        for (int o = 32; o >= 1; o >>= 1) { s += __shfl_xor(s, o); sq += __shfl_xor(sq, o); }
        int wid = tid >> 6, lane = tid & 63;
        if (lane == 0) { red[0][wid] = s; red[1][wid] = sq; }
        __syncthreads();
        float S = red[0][0] + red[0][1] + red[0][2] + red[0][3];
        float SQ = red[1][0] + red[1][1] + red[1][2] + red[1][3];
        float mu = S * (1.0f / 768.0f);
        float var = SQ * (1.0f / 768.0f) - mu * mu;
        float rs = rsqrtf(var + 1e-6f);
        unsigned short* op = fln + (size_t)grow * 768;
        op[j0] = f2bf((t0 - mu) * rs * ln_g[j0] + ln_b[j0]);
        op[j1] = f2bf((t1 - mu) * rs * ln_g[j1] + ln_b[j1]);
        op[j2] = f2bf((t2 - mu) * rs * ln_g[j2] + ln_b[j2]);
        __syncthreads();  // protect sS/sG/red reuse next row
    }
}

// ---------------------------------------------------------------------------
extern "C" void kernel_launch(void* const* d_in, const int* in_sizes, int n_in,
                              void* d_out, int out_size, void* d_ws, size_t ws_size,
                              hipStream_t stream)
{
    (void)in_sizes; (void)n_in; (void)out_size; (void)ws_size;
    const float* x     = (const float*)d_in[0];
    const float* y     = (const float*)d_in[1];
    const float* y2x   = (const float*)d_in[2];
    const float* x2y   = (const float*)d_in[3];
    const float* Wqkv  = (const float*)d_in[4];
    const float* Wpb   = (const float*)d_in[5];
    const float* bpb   = (const float*)d_in[6];
    const float* Wproj = (const float*)d_in[7];
    const float* bproj = (const float*)d_in[8];
    const float* ln_g  = (const float*)d_in[9];
    const float* ln_b  = (const float*)d_in[10];
    float* out = (float*)d_out;
    char* ws = (char*)d_ws;

    // workspace layout (bytes)
    unsigned short* lnbf   = (unsigned short*)(ws);                 // 65536*768*2   = 100663296
    unsigned short* qkvbf  = (unsigned short*)(ws + 100663296ull);  // 32768*2304*2  = 150994944
    unsigned short* flnbf  = (unsigned short*)(ws + 251658240ull);  // 65536*768*2   = 100663296
    unsigned short* WqkvT  = (unsigned short*)(ws + 352321536ull);  // 2304*768*2    = 3538944
    unsigned short* WprojT = (unsigned short*)(ws + 355860480ull);  // 768*768*2     = 1179648

    ln4_kernel<<<65536, 192, 0, stream>>>(x, y, y2x, x2y, ln_g, ln_b, lnbf);
    transpose_f32_to_bf16<<<(768 / 32) * (2304 / 32), 256, 0, stream>>>(Wqkv, WqkvT, 768, 2304);
    transpose_f32_to_bf16<<<(768 / 32) * (768 / 32), 256, 0, stream>>>(Wproj, WprojT, 768, 768);
    gemm_bt<false><<<(32768 / 128) * (2304 / 128), 256, 0, stream>>>(
        lnbf, WqkvT, (void*)qkvbf, nullptr, nullptr, 32768, 2304, 768);
    block_middle<<<8192, 256, 0, stream>>>(qkvbf, lnbf, Wpb, bpb, ln_g, ln_b, flnbf);
    gemm_bt<true><<<(65536 / 128) * (768 / 128), 256, 0, stream>>>(
        flnbf, WprojT, (void*)out, bproj, flnbf, 65536, 768, 768);
}

// Round 2
// 744.226 us; speedup vs baseline: 1.7169x; 1.7169x over previous
//
#include <hip/hip_runtime.h>

#define AS1 __attribute__((address_space(1)))
#define AS3 __attribute__((address_space(3)))

typedef __attribute__((ext_vector_type(8))) __bf16 bf16x8;
typedef __attribute__((ext_vector_type(4))) float f32x4;

__device__ __forceinline__ float bf2f(unsigned short u) {
    unsigned v = ((unsigned)u) << 16;
    float f;
    __builtin_memcpy(&f, &v, 4);
    return f;
}
__device__ __forceinline__ unsigned short f2bf(float f) {
    unsigned v;
    __builtin_memcpy(&v, &f, 4);
    unsigned r = (v + 0x7FFFu + ((v >> 16) & 1u)) >> 16;
    return (unsigned short)r;
}

// ---------------------------------------------------------------------------
// Kernel 1: LayerNorm of x / y / inial_y2x / inial_x2y -> bf16 [65536][768]
// rows [0,16384)=x, [16384,32768)=y, [32768,49152)=y2x, [49152,65536)=x2y
// ---------------------------------------------------------------------------
__global__ __launch_bounds__(192) void ln4_kernel(
    const float* __restrict__ x, const float* __restrict__ y,
    const float* __restrict__ y2x, const float* __restrict__ x2y,
    const float* __restrict__ g, const float* __restrict__ bb,
    unsigned short* __restrict__ out)
{
    __shared__ float red[2][3];
    int row = blockIdx.x;
    int c = row >> 14, rb = row & 16383;
    const float* src = (c == 0 ? x : c == 1 ? y : c == 2 ? y2x : x2y) + (size_t)rb * 768;
    int t = threadIdx.x;
    float4 v = ((const float4*)src)[t];
    float s = v.x + v.y + v.z + v.w;
    float sq = v.x * v.x + v.y * v.y + v.z * v.z + v.w * v.w;
#pragma unroll
    for (int o = 32; o >= 1; o >>= 1) { s += __shfl_xor(s, o); sq += __shfl_xor(sq, o); }
    int wid = t >> 6, lane = t & 63;
    if (lane == 0) { red[0][wid] = s; red[1][wid] = sq; }
    __syncthreads();
    float S = red[0][0] + red[0][1] + red[0][2];
    float SQ = red[1][0] + red[1][1] + red[1][2];
    float mu = S * (1.0f / 768.0f);
    float var = SQ * (1.0f / 768.0f) - mu * mu;
    float rs = rsqrtf(var + 1e-6f);
    float4 gv = ((const float4*)g)[t];
    float4 bv = ((const float4*)bb)[t];
    ushort4 o4;
    o4.x = f2bf((v.x - mu) * rs * gv.x + bv.x);
    o4.y = f2bf((v.y - mu) * rs * gv.y + bv.y);
    o4.z = f2bf((v.z - mu) * rs * gv.z + bv.z);
    o4.w = f2bf((v.w - mu) * rs * gv.w + bv.w);
    ((ushort4*)(out + (size_t)row * 768))[t] = o4;
}

// ---------------------------------------------------------------------------
// Kernel 2: transpose f32 [R][C] -> bf16 [C][R]
// ---------------------------------------------------------------------------
__global__ __launch_bounds__(256) void transpose_f32_to_bf16(
    const float* __restrict__ in, unsigned short* __restrict__ out, int R, int C)
{
    __shared__ float tile[32][33];
    int tilesC = C >> 5;
    int r0 = (blockIdx.x / tilesC) << 5;
    int c0 = (blockIdx.x % tilesC) << 5;
    int tx = threadIdx.x & 31, ty = threadIdx.x >> 5;
#pragma unroll
    for (int i = ty; i < 32; i += 8)
        tile[i][tx] = in[(size_t)(r0 + i) * C + c0 + tx];
    __syncthreads();
#pragma unroll
    for (int i = ty; i < 32; i += 8)
        out[(size_t)(c0 + i) * R + r0 + tx] = f2bf(tile[tx][i]);
}

// ---------------------------------------------------------------------------
// Kernel 3: bf16 MFMA GEMM, C = A[MxK] * B (B given as BT [N][K], row-major K)
// 128x128 tile, BK=64, 256 threads (4 waves, 2x2), 16x16x32 MFMA.
// EPI=false: out bf16.  EPI=true: out f32 = acc + bias[col] + resid[row][col].
// ---------------------------------------------------------------------------
template <bool EPI>
__global__ __launch_bounds__(256, 3) void gemm_bt(
    const unsigned short* __restrict__ A, const unsigned short* __restrict__ BT,
    void* __restrict__ outp, const float* __restrict__ bias,
    const unsigned short* __restrict__ resid, int M, int N, int K)
{
    __shared__ unsigned short sA[128 * 64];
    __shared__ unsigned short sB[128 * 64];
    const int tid = threadIdx.x;
    const int lane = tid & 63;
    const int wid = tid >> 6;
    const int wm = wid >> 1, wn = wid & 1;
    const int ntn = N >> 7;
    const int tm = blockIdx.x / ntn, tn = blockIdx.x % ntn;
    const int rowA0 = tm << 7, rowB0 = tn << 7;

    f32x4 acc[4][4];
    const f32x4 zero = {0.f, 0.f, 0.f, 0.f};
#pragma unroll
    for (int i = 0; i < 4; ++i)
#pragma unroll
        for (int j = 0; j < 4; ++j) acc[i][j] = zero;

    for (int k0 = 0; k0 < K; k0 += 64) {
#pragma unroll
        for (int r = 0; r < 4; ++r) {
            int idx = (r << 8) + tid;
            int arow = idx >> 3;
            int ce = (idx & 7) << 3;
            const unsigned short* gpA = A + (size_t)(rowA0 + arow) * K + k0 + ce;
            const unsigned short* gpB = BT + (size_t)(rowB0 + arow) * K + k0 + ce;
            __builtin_amdgcn_global_load_lds((const AS1 void*)gpA,
                                             (AS3 void*)((char*)sA + ((size_t)idx << 4)), 16, 0, 0);
            __builtin_amdgcn_global_load_lds((const AS1 void*)gpB,
                                             (AS3 void*)((char*)sB + ((size_t)idx << 4)), 16, 0, 0);
        }
        __syncthreads();
#pragma unroll
        for (int kk = 0; kk < 2; ++kk) {
            bf16x8 af[4], bfr[4];
            int kb = (kk << 6) + ((lane >> 4) << 4);
#pragma unroll
            for (int i = 0; i < 4; ++i) {
                af[i]  = *(const bf16x8*)((const char*)sA + ((wm << 6) + (i << 4) + (lane & 15)) * 128 + kb);
                bfr[i] = *(const bf16x8*)((const char*)sB + ((wn << 6) + (i << 4) + (lane & 15)) * 128 + kb);
            }
#pragma unroll
            for (int i = 0; i < 4; ++i)
#pragma unroll
                for (int j = 0; j < 4; ++j)
                    acc[i][j] = __builtin_amdgcn_mfma_f32_16x16x32_bf16(af[i], bfr[j], acc[i][j], 0, 0, 0);
        }
        __syncthreads();
    }

    const int r4 = (lane >> 4) << 2;
    const int cc = lane & 15;
    if (EPI) {
        float* o = (float*)outp;
#pragma unroll
        for (int i = 0; i < 4; ++i)
#pragma unroll
            for (int j = 0; j < 4; ++j) {
                int col = rowB0 + (wn << 6) + (j << 4) + cc;
                float bcol = bias[col];
#pragma unroll
                for (int r = 0; r < 4; ++r) {
                    int row = rowA0 + (wm << 6) + (i << 4) + r4 + r;
                    size_t off = (size_t)row * N + col;
                    o[off] = acc[i][j][r] + bcol + bf2f(resid[off]);
                }
            }
    } else {
        unsigned short* o = (unsigned short*)outp;
#pragma unroll
        for (int i = 0; i < 4; ++i)
#pragma unroll
            for (int j = 0; j < 4; ++j) {
                int col = rowB0 + (wn << 6) + (j << 4) + cc;
#pragma unroll
                for (int r = 0; r < 4; ++r) {
                    int row = rowA0 + (wm << 6) + (i << 4) + r4 + r;
                    o[(size_t)row * N + col] = f2bf(acc[i][j][r]);
                }
            }
    }
}

// ---------------------------------------------------------------------------
// Kernel 4 (rewritten): middle block via MFMA.
// Block = 16 global rows, 4 waves; wave w owns local rows 4w..4w+3.
// Phase A: q*k*scale -> per-head softmax (8-lane groups) -> g bf16 in sG.
// Phase B: [128,96] x WpbT[96,96] via mfma_16x16x32 (wave reads own sG rows).
// Phase C: +bpb -> sF f32; Phase D: +res, LN, bf16 out (per-wave shuffle LN).
// LDS: union( sWT[96][104] + sG[128][104] bf16 = 46.6KB , sF[16][776] f32 = 49.7KB )
// ---------------------------------------------------------------------------
__global__ __launch_bounds__(256) void middle_mfma(
    const unsigned short* __restrict__ qkv,
    const unsigned short* __restrict__ lnres,
    const float* __restrict__ Wpb, const float* __restrict__ bpb,
    const float* __restrict__ ln_g, const float* __restrict__ ln_b,
    unsigned short* __restrict__ fln)
{
    __shared__ __align__(16) char smem[49664];
    unsigned short* sWT = (unsigned short*)smem;            // [96][104] bf16 (WpbT)
    unsigned short* sG  = (unsigned short*)(smem + 19968);  // [128][104] bf16
    float* sF = (float*)smem;                               // [16][776] f32

    const int tid = threadIdx.x;
    const int lane = tid & 63;
    const int w = tid >> 6;
    const int l15 = lane & 15, lhi = lane >> 4;
    const float scale = 0.1020620726159658f;  // 96^-0.5

    // phase 0: Wpb^T (bf16) into sWT; Wpb read contiguous (L2-resident)
    for (int idx = tid; idx < 96 * 96; idx += 256) {
        int k = idx / 96, n = idx - k * 96;
        sWT[n * 104 + k] = f2bf(Wpb[idx]);
    }

    const int grow0 = blockIdx.x << 4;

    // phase A: softmax + g (bf16) into sG
    for (int rr = 0; rr < 4; ++rr) {
        int lr = (w << 2) + rr;
        int grow = grow0 + lr;
        int c = grow >> 14, b = grow & 16383;
        int qrow  = (c == 1 || c == 2) ? (16384 + b) : b;
        int kvrow = (c == 1 || c == 3) ? (16384 + b) : b;
        const unsigned short* qp = qkv + (size_t)qrow * 2304 + lane * 12;
        const unsigned short* kp = qkv + (size_t)kvrow * 2304 + 768 + lane * 12;
        const unsigned short* vp = qkv + (size_t)kvrow * 2304 + 1536 + lane * 12;
        float qf[12], kf[12], vf[12], s[12];
#pragma unroll
        for (int j = 0; j < 3; ++j) {
            ushort4 a = *(const ushort4*)(qp + j * 4);
            ushort4 d = *(const ushort4*)(kp + j * 4);
            ushort4 e = *(const ushort4*)(vp + j * 4);
            qf[j*4+0] = bf2f(a.x); qf[j*4+1] = bf2f(a.y); qf[j*4+2] = bf2f(a.z); qf[j*4+3] = bf2f(a.w);
            kf[j*4+0] = bf2f(d.x); kf[j*4+1] = bf2f(d.y); kf[j*4+2] = bf2f(d.z); kf[j*4+3] = bf2f(d.w);
            vf[j*4+0] = bf2f(e.x); vf[j*4+1] = bf2f(e.y); vf[j*4+2] = bf2f(e.z); vf[j*4+3] = bf2f(e.w);
        }
        float mx = -3.4e38f;
#pragma unroll
        for (int j = 0; j < 12; ++j) { s[j] = qf[j] * kf[j] * scale; mx = fmaxf(mx, s[j]); }
#pragma unroll
        for (int o = 4; o >= 1; o >>= 1) mx = fmaxf(mx, __shfl_xor(mx, o));  // 8-lane head group
        float sum = 0.f;
#pragma unroll
        for (int j = 0; j < 12; ++j) { s[j] = __expf(s[j] - mx); sum += s[j]; }
#pragma unroll
        for (int o = 4; o >= 1; o >>= 1) sum += __shfl_xor(sum, o);
        float inv = 1.0f / sum;
        int m = (lr << 3) + (lane >> 3);
        unsigned* gp = (unsigned*)(sG + m * 104 + (lane & 7) * 12);
#pragma unroll
        for (int j = 0; j < 6; ++j) {
            unsigned lo = f2bf(s[2*j]   * inv * vf[2*j]);
            unsigned hi = f2bf(s[2*j+1] * inv * vf[2*j+1]);
            gp[j] = lo | (hi << 16);
        }
    }
    __syncthreads();

    // phase B: MFMA  (wave w: m-tiles 2w, 2w+1 == its own sG rows)
    f32x4 acc[2][6];
    const f32x4 zero = {0.f, 0.f, 0.f, 0.f};
#pragma unroll
    for (int mi = 0; mi < 2; ++mi)
#pragma unroll
        for (int nj = 0; nj < 6; ++nj) acc[mi][nj] = zero;
#pragma unroll
    for (int ks = 0; ks < 3; ++ks) {
        bf16x8 bfrag[6];
#pragma unroll
        for (int nj = 0; nj < 6; ++nj)
            bfrag[nj] = *(const bf16x8*)(sWT + (nj * 16 + l15) * 104 + ks * 32 + lhi * 8);
#pragma unroll
        for (int mi = 0; mi < 2; ++mi) {
            bf16x8 afrag = *(const bf16x8*)(sG + (((w * 2 + mi) * 16) + l15) * 104 + ks * 32 + lhi * 8);
#pragma unroll
            for (int nj = 0; nj < 6; ++nj)
                acc[mi][nj] = __builtin_amdgcn_mfma_f32_16x16x32_bf16(afrag, bfrag[nj], acc[mi][nj], 0, 0, 0);
        }
    }
    __syncthreads();  // done reading sWT/sG before sF overwrites them

    // phase C: f + bpb -> sF   (C/D: col=lane&15, row=(lane>>4)*4+reg)
#pragma unroll
    for (int nj = 0; nj < 6; ++nj) {
        float bv = bpb[nj * 16 + l15];
#pragma unroll
        for (int mi = 0; mi < 2; ++mi) {
            int mbase = (w * 2 + mi) * 16 + lhi * 4;
#pragma unroll
            for (int reg = 0; reg < 4; ++reg) {
                int m = mbase + reg;
                int r = m >> 3, h = m & 7;
                sF[r * 776 + h * 96 + nj * 16 + l15] = acc[mi][nj][reg] + bv;
            }
        }
    }
    __syncthreads();

    // phase D: t = f + res; LN; bf16 out. Wave w owns rows 4w..4w+3 (own sF rows)
    for (int rr = 0; rr < 4; ++rr) {
        int lr = (w << 2) + rr;
        int grow = grow0 + lr;
        const float* fp = sF + lr * 776;
        const unsigned short* rp = lnres + (size_t)grow * 768;
        float t[12];
#pragma unroll
        for (int j = 0; j < 3; ++j) {
            f32x4 fv = *(const f32x4*)(fp + j * 256 + lane * 4);
            ushort4 rv = *(const ushort4*)(rp + j * 256 + lane * 4);
            t[j*4+0] = fv[0] + bf2f(rv.x);
            t[j*4+1] = fv[1] + bf2f(rv.y);
            t[j*4+2] = fv[2] + bf2f(rv.z);
            t[j*4+3] = fv[3] + bf2f(rv.w);
        }
        float s = 0.f, sq = 0.f;
#pragma unroll
        for (int j = 0; j < 12; ++j) { s += t[j]; sq += t[j] * t[j]; }
#pragma unroll
        for (int o = 32; o >= 1; o >>= 1) { s += __shfl_xor(s, o); sq += __shfl_xor(sq, o); }
        float mu = s * (1.0f / 768.0f);
        float var = sq * (1.0f / 768.0f) - mu * mu;
        float rs = rsqrtf(var + 1e-6f);
        unsigned short* op = fln + (size_t)grow * 768;
#pragma unroll
        for (int j = 0; j < 3; ++j) {
            float4 gvv = *(const float4*)(ln_g + j * 256 + lane * 4);
            float4 bvv = *(const float4*)(ln_b + j * 256 + lane * 4);
            ushort4 o4;
            o4.x = f2bf((t[j*4+0] - mu) * rs * gvv.x + bvv.x);
            o4.y = f2bf((t[j*4+1] - mu) * rs * gvv.y + bvv.y);
            o4.z = f2bf((t[j*4+2] - mu) * rs * gvv.z + bvv.z);
            o4.w = f2bf((t[j*4+3] - mu) * rs * gvv.w + bvv.w);
            *(ushort4*)(op + j * 256 + lane * 4) = o4;
        }
    }
}

// ---------------------------------------------------------------------------
extern "C" void kernel_launch(void* const* d_in, const int* in_sizes, int n_in,
                              void* d_out, int out_size, void* d_ws, size_t ws_size,
                              hipStream_t stream)
{
    (void)in_sizes; (void)n_in; (void)out_size; (void)ws_size;
    const float* x     = (const float*)d_in[0];
    const float* y     = (const float*)d_in[1];
    const float* y2x   = (const float*)d_in[2];
    const float* x2y   = (const float*)d_in[3];
    const float* Wqkv  = (const float*)d_in[4];
    const float* Wpb   = (const float*)d_in[5];
    const float* bpb   = (const float*)d_in[6];
    const float* Wproj = (const float*)d_in[7];
    const float* bproj = (const float*)d_in[8];
    const float* ln_g  = (const float*)d_in[9];
    const float* ln_b  = (const float*)d_in[10];
    float* out = (float*)d_out;
    char* ws = (char*)d_ws;

    unsigned short* lnbf   = (unsigned short*)(ws);                 // 65536*768*2
    unsigned short* qkvbf  = (unsigned short*)(ws + 100663296ull);  // 32768*2304*2
    unsigned short* flnbf  = (unsigned short*)(ws + 251658240ull);  // 65536*768*2
    unsigned short* WqkvT  = (unsigned short*)(ws + 352321536ull);  // 2304*768*2
    unsigned short* WprojT = (unsigned short*)(ws + 355860480ull);  // 768*768*2

    ln4_kernel<<<65536, 192, 0, stream>>>(x, y, y2x, x2y, ln_g, ln_b, lnbf);
    transpose_f32_to_bf16<<<(768 / 32) * (2304 / 32), 256, 0, stream>>>(Wqkv, WqkvT, 768, 2304);
    transpose_f32_to_bf16<<<(768 / 32) * (768 / 32), 256, 0, stream>>>(Wproj, WprojT, 768, 768);
    gemm_bt<false><<<(32768 / 128) * (2304 / 128), 256, 0, stream>>>(
        lnbf, WqkvT, (void*)qkvbf, nullptr, nullptr, 32768, 2304, 768);
    middle_mfma<<<4096, 256, 0, stream>>>(qkvbf, lnbf, Wpb, bpb, ln_g, ln_b, flnbf);
    gemm_bt<true><<<(65536 / 128) * (768 / 128), 256, 0, stream>>>(
        flnbf, WprojT, (void*)out, bproj, flnbf, 65536, 768, 768);
}